// Round 1
// baseline (36482.404 us; speedup 1.0000x reference)
//
#include <hip/hip_runtime.h>

typedef unsigned short u16;
typedef __attribute__((ext_vector_type(8))) short short8;
typedef __attribute__((ext_vector_type(4))) float f32x4;

#define B_ 2048
#define T_ 64
#define I_ 64
#define H_ 1024
#define G_ 4096

__device__ __forceinline__ float bf2f(u16 v) {
  union { float f; unsigned u; } x; x.u = ((unsigned)v) << 16; return x.f;
}
__device__ __forceinline__ u16 f2bf(float f) {
  union { float f; unsigned u; } x; x.f = f;
  unsigned r = x.u + 0x7fffu + ((x.u >> 16) & 1u);
  return (u16)(r >> 16);
}
__device__ __forceinline__ float sigm(float x) { return 1.0f / (1.0f + __expf(-x)); }
__device__ __forceinline__ float tanh_(float x) { return 1.0f - 2.0f / (__expf(2.0f * x) + 1.0f); }

__device__ __forceinline__ void async_copy16(const u16* g, u16* l) {
  __builtin_amdgcn_global_load_lds((__attribute__((address_space(1))) void*)(void*)g,
                                   (__attribute__((address_space(3))) void*)l, 16, 0, 0);
}

// -------------------- setup kernels --------------------

// x [B,T,I] fp32 -> xT [T,B,I] bf16
__global__ void k_transpose_x(const float* __restrict__ x, u16* __restrict__ xT) {
  int idx = blockIdx.x * 256 + threadIdx.x;  // over B*T*I = 8388608
  if (idx >= B_ * T_ * I_) return;
  int i = idx & 63;
  int t = (idx >> 6) & 63;
  int b = idx >> 12;
  xT[((size_t)t * B_ + b) * I_ + i] = f2bf(x[idx]);
}

// Build BT [4096][K] bf16: rows are permuted output cols n' = 4*unit + gate,
// k<K0 from U (recurrent), k>=K0 from W (input). Orig col j = gate*1024 + unit.
__global__ void k_build_bt(const float* __restrict__ U, const float* __restrict__ W,
                           u16* __restrict__ BT, int K0, int K) {
  int n = blockIdx.y;
  int k = blockIdx.x * 256 + threadIdx.x;
  if (k >= K) return;
  int j = (n & 3) * 1024 + (n >> 2);
  float v = (k < K0) ? U[(size_t)k * G_ + j] : W[(size_t)(k - K0) * G_ + j];
  BT[(size_t)n * K + k] = f2bf(v);
}

__global__ void k_build_bias(const float* __restrict__ b1, const float* __restrict__ b2,
                             const float* __restrict__ bd1, const float* __restrict__ bd2,
                             const float* __restrict__ d1W,
                             float* __restrict__ p1, float* __restrict__ p2,
                             float* __restrict__ pd1, float* __restrict__ pd2,
                             float* __restrict__ pd1W) {
  int n = blockIdx.x * 256 + threadIdx.x;
  if (n >= G_) return;
  int j = (n & 3) * 1024 + (n >> 2);
  p1[n] = b1[j]; p2[n] = b2[j]; pd1[n] = bd1[j]; pd2[n] = bd2[j];
  pd1W[n] = d1W[j];
}

// -------------------- fused GEMM + LSTM cell --------------------
// z[m, n'] = sum_k A[m,k] * BT[n',k]  (A = [A0 seg | A1 seg] along K)
// then per (m, unit): i,f,g,o = z cols 4u..4u+3 (+bias, + optional gen*d1_W),
// c = f*c + i*g; h = o*tanh(c) -> hout bf16.
__global__ __launch_bounds__(256, 3)
void k_gemm(const u16* __restrict__ A0, int lda0, int kt0,
            const u16* __restrict__ A1, int lda1, int kt1,
            const u16* __restrict__ BT, int ldb,
            const float* __restrict__ biasp,
            const float* __restrict__ evec,
            const float* __restrict__ escal, int estride,
            float* __restrict__ cst, u16* __restrict__ hout) {
  __shared__ u16 smem[16384];  // 32 KB: A tile [128][64], B tile [128][64]
  const int tid = threadIdx.x;
  const int lane = tid & 63;
  const int w = tid >> 6;
  const int m0 = blockIdx.x << 7;
  const int n0 = blockIdx.y << 7;
  const int KT = kt0 + kt1;

  // staging: thread covers LDS row rs = s*32 + tid/8, chunk c = tid&7;
  // global chunk fetched = c ^ (rs&7)  (XOR swizzle applied on the global side)
  const int r_ = tid >> 3, c_ = tid & 7;
  const u16* pA0[4]; const u16* pA1[4]; const u16* pB[4];
#pragma unroll
  for (int s = 0; s < 4; ++s) {
    int rs = (s << 5) + r_;
    int ch = (c_ ^ (rs & 7)) << 3;
    pA0[s] = A0 + (size_t)(m0 + rs) * lda0 + ch;
    pA1[s] = A1 ? (A1 + (size_t)(m0 + rs) * lda1 + ch) : pA0[s];
    pB[s] = BT + (size_t)(n0 + rs) * ldb + ch;
  }
  u16* ldsA = smem + (w << 9);
  u16* ldsB = smem + 8192 + (w << 9);

  f32x4 acc[4][4];
#pragma unroll
  for (int i = 0; i < 4; ++i)
#pragma unroll
    for (int j = 0; j < 4; ++j) acc[i][j] = (f32x4){0.f, 0.f, 0.f, 0.f};

  const int wm = (w >> 1) << 6, wn = (w & 1) << 6;
  const int q = lane >> 4, l15 = lane & 15, l7 = lane & 7;
  int aoffr[4], boffr[4];
#pragma unroll
  for (int i = 0; i < 4; ++i) {
    aoffr[i] = (wm + (i << 4) + l15) << 6;
    boffr[i] = 8192 + ((wn + (i << 4) + l15) << 6);
  }

  for (int kt = 0; kt < KT; ++kt) {
    __syncthreads();  // previous tile's compute done
    bool seg0 = (kt < kt0);
#pragma unroll
    for (int s = 0; s < 4; ++s) {
      const u16* ga = seg0 ? (pA0[s] + (size_t)kt * 64)
                           : (pA1[s] + (size_t)(kt - kt0) * 64);
      async_copy16(ga, ldsA + (s << 11));
      async_copy16(pB[s] + (size_t)kt * 64, ldsB + (s << 11));
    }
    __syncthreads();  // drains vmcnt(0) -> LDS visible
#pragma unroll
    for (int ks = 0; ks < 2; ++ks) {
      const int sw = ((((ks << 2) + q) ^ l7) << 3);
      short8 af[4], bfr[4];
#pragma unroll
      for (int i = 0; i < 4; ++i) {
        af[i] = *(const short8*)&smem[aoffr[i] + sw];
        bfr[i] = *(const short8*)&smem[boffr[i] + sw];
      }
#pragma unroll
      for (int i = 0; i < 4; ++i)
#pragma unroll
        for (int j = 0; j < 4; ++j)
          acc[i][j] = __builtin_amdgcn_mfma_f32_16x16x32_bf16(af[i], bfr[j], acc[i][j], 0, 0, 0);
    }
  }

  // ---- fused LSTM-cell epilogue (LDS reshuffle: C-layout -> per-lane 4 gates) ----
  __syncthreads();
  float* ep = (float*)smem + w * 1280;  // per-wave [64][20] fp32 region
  const int ul = lane & 3, ml = lane >> 2;
  const int ubase = (n0 >> 2) + (wn >> 2);
#pragma unroll 1
  for (int tj = 0; tj < 4; ++tj) {
#pragma unroll
    for (int ti = 0; ti < 4; ++ti)
#pragma unroll
      for (int v = 0; v < 4; ++v)
        ep[((ti << 4) + (q << 2) + v) * 20 + l15] = acc[ti][tj][v];
    __syncthreads();
#pragma unroll
    for (int p = 0; p < 4; ++p) {
      int row = ml + (p << 4);
      f32x4 z = *(const f32x4*)&ep[row * 20 + (ul << 2)];
      int gm = m0 + wm + row;
      int gu = ubase + (tj << 2) + ul;
      const f32x4 bb = *(const f32x4*)&biasp[gu << 2];
      z.x += bb.x; z.y += bb.y; z.z += bb.z; z.w += bb.w;
      if (evec) {  // d1: + gen[m] * d1_W[n']  (K=1 input folded here, fp32)
        float gs = escal[(size_t)gm * estride];
        const f32x4 ev = *(const f32x4*)&evec[gu << 2];
        z.x += gs * ev.x; z.y += gs * ev.y; z.z += gs * ev.z; z.w += gs * ev.w;
      }
      float ig = sigm(z.x), fg = sigm(z.y), gg = tanh_(z.z), og = sigm(z.w);
      size_t ci = ((size_t)gm << 10) + gu;
      float cn = fg * cst[ci] + ig * gg;
      cst[ci] = cn;
      hout[ci] = f2bf(og * tanh_(cn));
    }
    __syncthreads();
  }
}

// -------------------- small kernels --------------------

// g3: LSTM with H=1. One wave per batch row.
__global__ void k_g3(const u16* __restrict__ h2, const float* __restrict__ W,
                     const float* __restrict__ Uv, const float* __restrict__ bv,
                     float* __restrict__ c3, float* __restrict__ h3,
                     float* __restrict__ gen, int t) {
  int b = blockIdx.x * 4 + (threadIdx.x >> 6);
  int lane = threadIdx.x & 63;
  float a0 = 0.f, a1 = 0.f, a2 = 0.f, a3 = 0.f;
  for (int k = lane; k < H_; k += 64) {
    float hv = bf2f(h2[((size_t)b << 10) + k]);
    const f32x4 wv = *(const f32x4*)&W[k << 2];
    a0 += hv * wv.x; a1 += hv * wv.y; a2 += hv * wv.z; a3 += hv * wv.w;
  }
  for (int off = 32; off; off >>= 1) {
    a0 += __shfl_down(a0, off);
    a1 += __shfl_down(a1, off);
    a2 += __shfl_down(a2, off);
    a3 += __shfl_down(a3, off);
  }
  if (lane == 0) {
    float hp = h3[b];
    float zi = a0 + hp * Uv[0] + bv[0];
    float zf = a1 + hp * Uv[1] + bv[1];
    float zg = a2 + hp * Uv[2] + bv[2];
    float zo = a3 + hp * Uv[3] + bv[3];
    float cn = sigm(zf) * c3[b] + sigm(zi) * tanh_(zg);
    c3[b] = cn;
    float hn = sigm(zo) * tanh_(cn);
    h3[b] = hn;
    gen[b * T_ + t] = hn;
  }
}

// final dense: disc[b,t] = hd2[b,:] . do_W + do_b
__global__ void k_dense(const u16* __restrict__ hd2, const float* __restrict__ wv,
                        const float* __restrict__ bs, float* __restrict__ disc, int t) {
  int b = blockIdx.x * 4 + (threadIdx.x >> 6);
  int lane = threadIdx.x & 63;
  float a = 0.f;
  for (int k = lane; k < H_; k += 64)
    a += bf2f(hd2[((size_t)b << 10) + k]) * wv[k];
  for (int off = 32; off; off >>= 1) a += __shfl_down(a, off);
  if (lane == 0) disc[b * T_ + t] = a + bs[0];
}

// -------------------- launcher --------------------

extern "C" void kernel_launch(void* const* d_in, const int* in_sizes, int n_in,
                              void* d_out, int out_size, void* d_ws, size_t ws_size,
                              hipStream_t stream) {
  const float* x   = (const float*)d_in[0];
  const float* g1W = (const float*)d_in[1];
  const float* g1U = (const float*)d_in[2];
  const float* g1b = (const float*)d_in[3];
  const float* g2W = (const float*)d_in[4];
  const float* g2U = (const float*)d_in[5];
  const float* g2b = (const float*)d_in[6];
  const float* g3W = (const float*)d_in[7];
  const float* g3U = (const float*)d_in[8];
  const float* g3b = (const float*)d_in[9];
  const float* d1W = (const float*)d_in[10];
  const float* d1U = (const float*)d_in[11];
  const float* d1b = (const float*)d_in[12];
  const float* d2W = (const float*)d_in[13];
  const float* d2U = (const float*)d_in[14];
  const float* d2b = (const float*)d_in[15];
  const float* doW = (const float*)d_in[16];
  const float* dob = (const float*)d_in[17];

  char* ws = (char*)d_ws;
  u16* xT    = (u16*)(ws + 0);            // 16,777,216
  u16* BT1   = (u16*)(ws + 16777216);     //  8,912,896  [4096][1088]
  u16* BT2   = (u16*)(ws + 25690112);     // 16,777,216  [4096][2048]
  u16* BTd1  = (u16*)(ws + 42467328);     //  8,388,608  [4096][1024]
  u16* BTd2  = (u16*)(ws + 50855936);     // 16,777,216  [4096][2048]
  float* pb1  = (float*)(ws + 67633152);
  float* pb2  = (float*)(ws + 67649536);
  float* pbd1 = (float*)(ws + 67665920);
  float* pbd2 = (float*)(ws + 67682304);
  float* pd1W = (float*)(ws + 67698688);
  const size_t Z0 = 67715072;             // zeroed region start
  float* c1  = (float*)(ws + Z0);
  float* c2  = (float*)(ws + Z0 + 8388608);
  float* cd1 = (float*)(ws + Z0 + 16777216);
  float* cd2 = (float*)(ws + Z0 + 25165824);
  u16* h1[2]  = {(u16*)(ws + Z0 + 33554432), (u16*)(ws + Z0 + 37748736)};
  u16* h2[2]  = {(u16*)(ws + Z0 + 41943040), (u16*)(ws + Z0 + 46137344)};
  u16* hd1[2] = {(u16*)(ws + Z0 + 50331648), (u16*)(ws + Z0 + 54525952)};
  u16* hd2[2] = {(u16*)(ws + Z0 + 58720256), (u16*)(ws + Z0 + 62914560)};
  float* c3 = (float*)(ws + Z0 + 67108864);
  float* h3 = (float*)(ws + Z0 + 67117056);
  const size_t ZBYTES = 67125248;

  // setup (re-done every launch: ws is poisoned before each timed call)
  k_transpose_x<<<32768, 256, 0, stream>>>(x, xT);
  k_build_bt<<<dim3(5, 4096), 256, 0, stream>>>(g1U, g1W, BT1, 1024, 1088);
  k_build_bt<<<dim3(8, 4096), 256, 0, stream>>>(g2U, g2W, BT2, 1024, 2048);
  k_build_bt<<<dim3(4, 4096), 256, 0, stream>>>(d1U, nullptr, BTd1, 1024, 1024);
  k_build_bt<<<dim3(8, 4096), 256, 0, stream>>>(d2U, d2W, BTd2, 1024, 2048);
  k_build_bias<<<16, 256, 0, stream>>>(g1b, g2b, d1b, d2b, d1W, pb1, pb2, pbd1, pbd2, pd1W);
  (void)hipMemsetAsync(ws + Z0, 0, ZBYTES, stream);

  float* gen = (float*)d_out;
  float* disc = gen + (size_t)B_ * T_;
  dim3 grid(16, 32), blk(256);
  for (int t = 0; t < T_; ++t) {
    int rp = t & 1, wp = rp ^ 1;
    // g1: z = h1_prev @ U1 + x_t @ W1
    k_gemm<<<grid, blk, 0, stream>>>(h1[rp], H_, 16, xT + (size_t)t * B_ * I_, I_, 1,
                                     BT1, 1088, pb1, nullptr, nullptr, 0, c1, h1[wp]);
    // g2: z = h2_prev @ U2 + h1_cur @ W2
    k_gemm<<<grid, blk, 0, stream>>>(h2[rp], H_, 16, h1[wp], H_, 16,
                                     BT2, 2048, pb2, nullptr, nullptr, 0, c2, h2[wp]);
    // g3 (H=1) -> gen[:, t]
    k_g3<<<512, blk, 0, stream>>>(h2[wp], g3W, g3U, g3b, c3, h3, gen, t);
    // d1: z = hd1_prev @ d1U (+ gen_t * d1W in epilogue)
    k_gemm<<<grid, blk, 0, stream>>>(hd1[rp], H_, 16, nullptr, 0, 0,
                                     BTd1, 1024, pbd1, pd1W, gen + t, T_, cd1, hd1[wp]);
    // d2: z = hd2_prev @ d2U + hd1_cur @ d2W
    k_gemm<<<grid, blk, 0, stream>>>(hd2[rp], H_, 16, hd1[wp], H_, 16,
                                     BTd2, 2048, pbd2, nullptr, nullptr, 0, cd2, hd2[wp]);
    // dense -> disc[:, t]
    k_dense<<<512, blk, 0, stream>>>(hd2[wp], doW, dob, disc, t);
  }
  (void)in_sizes; (void)n_in; (void)out_size; (void)ws_size;
}